// Round 1
// baseline (3373.653 us; speedup 1.0000x reference)
//
#include <hip/hip_runtime.h>
#include <hip/hip_bf16.h>

// GraphConvLayer: out = relu(A_norm @ (X@W + b))
// Reassociated: Y = A@X (sparse gather, ~12.8 nnz/row), out = relu(Y@W + rowsum(A)[n]*b[d])
// x: [1024, 543, 256] f32; W: [256,256] f32; b: [256]; A: [543,543] f32; out: [1024,543,256] f32

#define NND    543
#define FEATD  256
#define OUTD   256
#define NTILE  128
#define NTILES 5          // ceil(543/128)
#define CAP    40         // max stored nnz per row (mean 12.8, +8.6 sigma headroom; dense fallback otherwise)
#define CHUNK  64         // x rows staged in LDS per step
#define NCHUNK 9          // ceil(543/64)
#define BTOT   1024       // B*T
#define GRID   (BTOT*NTILES)

typedef __attribute__((ext_vector_type(8))) short short8;
typedef __attribute__((ext_vector_type(4))) float f32x4;

struct Ent { unsigned short m; unsigned short pad; float a; }; // 8 B

// ---- workspace CSR layout ----
#define WS_ENT_OFF 0
#define WS_ENT_BYTES (NND*CAP*8)                    // 173760
#define WS_RS_OFF  WS_ENT_BYTES                     // rowsum f32[543]
#define WS_ST_OFF  (WS_RS_OFF + NND*4)              // starts u16[543][10]
#define WS_NEED    (WS_ST_OFF + NND*(NCHUNK+1)*2)   // ~187 KB

// ---- LDS layout (bytes) ----
#define LDS_ENT 0                    // Ent[128][CAP] = 40960   (dead after gather)
#define LDS_X   40960                // bf16 x-chunk [64][256] = 32768 (dead after gather)
#define LDS_RS  73728                // f32 rowsum[128] (persistent)
#define LDS_ST  74240                // u16 starts[128][10] = 2560 (persistent)
#define LDS_TOT 76800
// Y bf16 [128][256] swizzled lives at byte 0..65536 (overlaps ENT+X after gather)

__device__ __forceinline__ unsigned short f2bf(float f) {   // RNE f32 -> bf16 bits
  unsigned int u = __builtin_bit_cast(unsigned int, f);
  u += 0x7fffu + ((u >> 16) & 1u);
  return (unsigned short)(u >> 16);
}
__device__ __forceinline__ float bflo(unsigned int u) { return __builtin_bit_cast(float, u << 16); }
__device__ __forceinline__ float bfhi(unsigned int u) { return __builtin_bit_cast(float, u & 0xffff0000u); }

__global__ void build_csr(const float* __restrict__ A, char* __restrict__ ws) {
  const int n = blockIdx.x * blockDim.x + threadIdx.x;
  if (n >= NND) return;
  Ent* ent = (Ent*)(ws + WS_ENT_OFF) + n * CAP;
  float* rs = (float*)(ws + WS_RS_OFF);
  unsigned short* st = (unsigned short*)(ws + WS_ST_OFF) + n * (NCHUNK + 1);
  const float* arow = A + (size_t)n * NND;
  float s = 0.f; int cnt = 0;
  for (int c = 0; c < NCHUNK; c++) {
    st[c] = (unsigned short)min(cnt, CAP);
    const int mend = min((c + 1) * CHUNK, NND);
    for (int m = c * CHUNK; m < mend; m++) {
      const float a = arow[m];
      s += a;
      if (a != 0.f) {
        if (cnt < CAP) { ent[cnt].m = (unsigned short)m; ent[cnt].pad = 0; ent[cnt].a = a; }
        cnt++;
      }
    }
  }
  st[NCHUNK] = (unsigned short)cnt;   // >CAP => row uses dense fallback
  rs[n] = s;
}

__global__ __launch_bounds__(512, 4)  // VGPR<=128 -> 2 blocks/CU with 75KB LDS
void gcn_main(const float* __restrict__ x, const float* __restrict__ Wm,
              const float* __restrict__ bias, const float* __restrict__ A,
              float* __restrict__ out, const char* __restrict__ ws, int use_ws)
{
  __shared__ __align__(16) char lds[LDS_TOT];
  Ent* ents = (Ent*)(lds + LDS_ENT);
  float* rs_lds = (float*)(lds + LDS_RS);
  unsigned short* st_lds = (unsigned short*)(lds + LDS_ST);
  unsigned short* xlds = (unsigned short*)(lds + LDS_X);

  const int tid = threadIdx.x;
  // XCD-chunked swizzle: 5 blocks sharing one bt land on the same XCD (x L2 reuse)
  const int p = blockIdx.x;
  const int L = (p & 7) * (GRID / 8) + (p >> 3);
  const int bt = L / NTILES;
  const int tile = L - bt * NTILES;
  const int n0 = tile * NTILE;

  // ---------- phase 1: per-row adjacency lists into LDS ----------
  if (use_ws) {
    const unsigned int* esrc = (const unsigned int*)(ws + WS_ENT_OFF);
    unsigned int* edst = (unsigned int*)ents;
    for (int i = tid; i < NTILE * CAP * 2; i += 512) {
      const int r = i / (CAP * 2);
      const int n = n0 + r;
      edst[i] = (n < NND) ? esrc[n * (CAP * 2) + (i - r * (CAP * 2))] : 0u;
    }
    const unsigned short* ssrc = (const unsigned short*)(ws + WS_ST_OFF);
    for (int i = tid; i < NTILE * (NCHUNK + 1); i += 512) {
      const int r = i / (NCHUNK + 1);
      const int n = n0 + r;
      st_lds[i] = (n < NND) ? ssrc[n * (NCHUNK + 1) + (i - r * (NCHUNK + 1))] : (unsigned short)0;
    }
    if (tid < NTILE) {
      const int n = n0 + tid;
      rs_lds[tid] = (n < NND) ? ((const float*)(ws + WS_RS_OFF))[n] : 0.f;
    }
  } else {
    // fallback: in-block scan (threads 0..127)
    if (tid < NTILE) {
      const int n = n0 + tid;
      float s = 0.f; int cnt = 0;
      if (n < NND) {
        const float* arow = A + (size_t)n * NND;
        for (int c = 0; c < NCHUNK; c++) {
          st_lds[tid * (NCHUNK + 1) + c] = (unsigned short)min(cnt, CAP);
          const int mend = min((c + 1) * CHUNK, NND);
          for (int m = c * CHUNK; m < mend; m++) {
            const float a = arow[m];
            s += a;
            if (a != 0.f) {
              if (cnt < CAP) { ents[tid * CAP + cnt].m = (unsigned short)m; ents[tid * CAP + cnt].a = a; }
              cnt++;
            }
          }
        }
      } else {
        for (int c = 0; c < NCHUNK; c++) st_lds[tid * (NCHUNK + 1) + c] = 0;
      }
      st_lds[tid * (NCHUNK + 1) + NCHUNK] = (unsigned short)cnt;
      rs_lds[tid] = s;
    }
  }
  __syncthreads();

  // ---------- phase 2: Y = A@X, Y rows in registers, x chunked through LDS ----------
  const int w = tid >> 6;        // wave 0..7 owns rows w*16..w*16+15
  const int lane = tid & 63;     // lane -> feature group f = 4*lane..4*lane+3

  f32x4 y[16];
  #pragma unroll
  for (int i = 0; i < 16; i++) y[i] = (f32x4){0.f, 0.f, 0.f, 0.f};

  const float* xbt = x + (size_t)bt * (NND * FEATD);

  for (int c = 0; c < NCHUNK; c++) {
    const int m0 = c * CHUNK;
    const int rows = min(CHUNK, NND - m0);
    // stage chunk: fp32 -> bf16, coalesced
    #pragma unroll
    for (int k = 0; k < 8; k++) {
      const int fl = tid + k * 512;          // 0..4095 float4 slots
      const int row = fl >> 6;
      const int f4 = fl & 63;
      if (row < rows) {
        const float4 v = *(const float4*)(xbt + (m0 + row) * FEATD + f4 * 4);
        uint2 u;
        u.x = (unsigned int)f2bf(v.x) | ((unsigned int)f2bf(v.y) << 16);
        u.y = (unsigned int)f2bf(v.z) | ((unsigned int)f2bf(v.w) << 16);
        *(uint2*)(xlds + row * 256 + f4 * 4) = u;
      }
    }
    __syncthreads();
    // gather
    #pragma unroll
    for (int i = 0; i < 16; i++) {
      const int r = w * 16 + i;
      const int tot = st_lds[r * (NCHUNK + 1) + NCHUNK];
      if (tot <= CAP) {
        int j = st_lds[r * (NCHUNK + 1) + c];
        const int j1 = st_lds[r * (NCHUNK + 1) + c + 1];
        for (; j < j1; j++) {
          const Ent e = ents[r * CAP + j];
          const uint2 u = *(const uint2*)(xlds + (e.m - m0) * 256 + lane * 4);
          y[i].x += e.a * bflo(u.x);
          y[i].y += e.a * bfhi(u.x);
          y[i].z += e.a * bflo(u.y);
          y[i].w += e.a * bfhi(u.y);
        }
      } else {
        // dense fallback for pathological rows (never triggers for 2% density)
        const float* arow = A + (size_t)(n0 + r) * NND;
        for (int mm = 0; mm < rows; mm++) {
          const float a = arow[m0 + mm];
          if (a != 0.f) {
            const uint2 u = *(const uint2*)(xlds + mm * 256 + lane * 4);
            y[i].x += a * bflo(u.x);
            y[i].y += a * bfhi(u.x);
            y[i].z += a * bflo(u.y);
            y[i].w += a * bfhi(u.y);
          }
        }
      }
    }
    __syncthreads();
  }

  // ---------- phase 3: Y -> LDS bf16 [128][256], XOR-swizzled (T2) ----------
  #pragma unroll
  for (int i = 0; i < 16; i++) {
    const int r = w * 16 + i;
    uint2 u;
    u.x = (unsigned int)f2bf(y[i].x) | ((unsigned int)f2bf(y[i].y) << 16);
    u.y = (unsigned int)f2bf(y[i].z) | ((unsigned int)f2bf(y[i].w) << 16);
    const int byte = r * 512 + ((lane * 8) ^ ((r & 7) << 4));
    *(uint2*)(lds + byte) = u;
  }
  __syncthreads();

  // ---------- phase 4: out = relu(Y@W + rowsum*b), mfma 16x16x32 bf16 ----------
  const int krow = (lane >> 4) * 8;   // A/B frag: k = krow + e
  const int cl = lane & 15;
  for (int dt = 0; dt < 2; dt++) {    // two passes of 16 d-cols each, keeps VGPR <= 128
    const int d0 = w * 32 + dt * 16 + cl;
    short8 wf[8];
    #pragma unroll
    for (int ks = 0; ks < 8; ks++) {
      #pragma unroll
      for (int e = 0; e < 8; e++) {
        wf[ks][e] = (short)f2bf(Wm[(ks * 32 + krow + e) * OUTD + d0]);
      }
    }
    f32x4 acc[8];
    #pragma unroll
    for (int mt = 0; mt < 8; mt++) acc[mt] = (f32x4){0.f, 0.f, 0.f, 0.f};
    #pragma unroll
    for (int ks = 0; ks < 8; ks++) {
      #pragma unroll
      for (int mt = 0; mt < 8; mt++) {
        const int r = mt * 16 + cl;
        const int kb = (ks * 64 + krow * 2) ^ ((r & 7) << 4);
        const short8 af = *(const short8*)(lds + r * 512 + kb);
        acc[mt] = __builtin_amdgcn_mfma_f32_16x16x32_bf16(af, wf[ks], acc[mt], 0, 0, 0);
      }
    }
    const float bv = bias[d0];
    #pragma unroll
    for (int mt = 0; mt < 8; mt++) {
      #pragma unroll
      for (int q = 0; q < 4; q++) {
        const int r = mt * 16 + (lane >> 4) * 4 + q;   // C/D: col=lane&15, row=(lane>>4)*4+reg
        const int n = n0 + r;
        if (n < NND) {
          float v = acc[mt][q] + rs_lds[r] * bv;
          v = fmaxf(v, 0.f);
          out[((size_t)bt * NND + n) * OUTD + d0] = v;
        }
      }
    }
  }
}

extern "C" void kernel_launch(void* const* d_in, const int* in_sizes, int n_in,
                              void* d_out, int out_size, void* d_ws, size_t ws_size,
                              hipStream_t stream) {
  const float* x  = (const float*)d_in[0];
  const float* Wm = (const float*)d_in[1];
  const float* b  = (const float*)d_in[2];
  const float* A  = (const float*)d_in[3];
  float* out = (float*)d_out;
  const int use_ws = (d_ws != nullptr && ws_size >= (size_t)WS_NEED) ? 1 : 0;
  if (use_ws) build_csr<<<(NND + 127) / 128, 128, 0, stream>>>(A, (char*)d_ws);
  gcn_main<<<GRID, 512, 0, stream>>>(x, Wm, b, A, out, (const char*)d_ws, use_ws);
}